// Round 1
// baseline (412.620 us; speedup 1.0000x reference)
//
#include <hip/hip_runtime.h>
#include <hip/hip_bf16.h>
#include <stdint.h>

// ---------------------------------------------------------------------------
// AstrocyteMemoryModule: bf16 MFMA pipeline.
//   Wc{q,k,v} = Wi{q,k,v} @ W{q,k,v}   (fused projection weights, D x D)
//   kh = mk @ Wck^T + bck ; vh = mv @ Wcv^T + bcv   (the big GEMMs, M x D)
//   qh = (x @ Wcq^T + bcq) * 1/8
//   scores[h,b,m] = qh_h @ kh_h^T ; softmax ; ctx = attn @ vh_h
//   tail: ms -> gate -> out  (B=64 row chain with fused epilogues)
// ---------------------------------------------------------------------------

typedef __bf16 bf16;
typedef __bf16 bf16x4 __attribute__((ext_vector_type(4)));
typedef __bf16 bf16x8 __attribute__((ext_vector_type(8)));
typedef float f32x4 __attribute__((ext_vector_type(4)));

#define D_ 1024
#define M_ 8192
#define B_ 64
#define H_ 16

static __device__ __forceinline__ void gload16(const void* g, void* l) {
  __builtin_amdgcn_global_load_lds(
      (const __attribute__((address_space(1))) void*)g,
      (__attribute__((address_space(3))) void*)l, 16, 0, 0);
}

// ------------------------------- converts ----------------------------------
struct CvtDesc { const float* src; bf16* dst; int n; int row_len; int row_stride; };
struct CvtArgs { CvtDesc d[10]; };

__global__ __launch_bounds__(256) void cvt_multi(CvtArgs a) {
  CvtDesc dd = a.d[blockIdx.y];
  int i = (blockIdx.x * 256 + threadIdx.x) * 4;
  if (i >= dd.n) return;
  float4 v = *(const float4*)(dd.src + i);
  int r = i / dd.row_len;
  int c = i - r * dd.row_len;
  bf16x4 o = { (bf16)v.x, (bf16)v.y, (bf16)v.z, (bf16)v.w };
  *(bf16x4*)(dd.dst + (int64_t)r * dd.row_stride + c) = o;
}

// transpose+convert Wq,Wk,Wv (fp32 DxD -> bf16 transposed), z picks tensor
__global__ __launch_bounds__(256) void transpose_cvt3(
    const float* __restrict__ s0, const float* __restrict__ s1,
    const float* __restrict__ s2, bf16* __restrict__ dst) {
  const float* src = blockIdx.z == 0 ? s0 : blockIdx.z == 1 ? s1 : s2;
  bf16* out = dst + (int64_t)blockIdx.z * D_ * D_;
  __shared__ bf16 tile[32][33];
  int tx = threadIdx.x & 31, ty = threadIdx.x >> 5;
  int r0 = blockIdx.y * 32, c0 = blockIdx.x * 32;
#pragma unroll
  for (int i = 0; i < 32; i += 8)
    tile[ty + i][tx] = (bf16)src[(int64_t)(r0 + ty + i) * D_ + c0 + tx];
  __syncthreads();
#pragma unroll
  for (int i = 0; i < 32; i += 8)
    out[(int64_t)(c0 + ty + i) * D_ + r0 + tx] = tile[tx][ty + i];
}

// bf16 transpose of vh (M_ x D_) -> vhT (D_ x M_)
__global__ __launch_bounds__(256) void transpose_vh(const bf16* __restrict__ in,
                                                    bf16* __restrict__ out) {
  __shared__ bf16 tile[64][66];
  const int t = threadIdx.x;
  const int c0 = blockIdx.x * 64;  // col base (n in vh)
  const int r0 = blockIdx.y * 64;  // row base (m)
  const int v4 = (t & 15) * 4, rr = t >> 4;
#pragma unroll
  for (int i = 0; i < 64; i += 16) {
    bf16x4 u = *(const bf16x4*)(in + (int64_t)(r0 + rr + i) * D_ + c0 + v4);
    tile[rr + i][v4 + 0] = u.x; tile[rr + i][v4 + 1] = u.y;
    tile[rr + i][v4 + 2] = u.z; tile[rr + i][v4 + 3] = u.w;
  }
  __syncthreads();
#pragma unroll
  for (int i = 0; i < 64; i += 16) {
    int oc = rr + i;
    bf16x4 o = { tile[v4 + 0][oc], tile[v4 + 1][oc],
                 tile[v4 + 2][oc], tile[v4 + 3][oc] };
    *(bf16x4*)(out + (int64_t)(c0 + oc) * M_ + r0 + v4) = o;
  }
}

// bc[z*D+n] = sum_l inproj[z*D+n][l]*b_z[l] + inproj_b[z*D+n]
__global__ __launch_bounds__(256) void bias_combine(
    const float* __restrict__ inw, const float* __restrict__ inb,
    const float* __restrict__ bq, const float* __restrict__ bk,
    const float* __restrict__ bv, float* __restrict__ bc) {
  int z = blockIdx.y, n = blockIdx.x;
  const float* Wi = inw + ((int64_t)z * D_ + n) * D_;
  const float* b = z == 0 ? bq : z == 1 ? bk : bv;
  float acc = 0.f;
  for (int l = threadIdx.x; l < D_; l += 256) acc += Wi[l] * b[l];
#pragma unroll
  for (int m = 32; m; m >>= 1) acc += __shfl_xor(acc, m, 64);
  __shared__ float red[4];
  if ((threadIdx.x & 63) == 0) red[threadIdx.x >> 6] = acc;
  __syncthreads();
  if (threadIdx.x == 0)
    bc[z * D_ + n] = red[0] + red[1] + red[2] + red[3] + inb[z * D_ + n];
}

// ------------------------- big GEMM: C = A @ B^T ---------------------------
// 128x128 tile, BK=32, 4 waves (2x2 of 64x64), bf16 out (+bias). Batched by z.
__global__ __launch_bounds__(256) void gemm_bt_big(
    const bf16* __restrict__ A, int lda, int64_t sA,
    const bf16* __restrict__ Bm, int ldb, int64_t sB,
    bf16* __restrict__ C, int ldc, int64_t sC,
    const float* __restrict__ bias, int64_t sbias, int K) {
  const int z = blockIdx.z;
  A += (int64_t)z * sA; Bm += (int64_t)z * sB; C += (int64_t)z * sC;
  if (bias) bias += (int64_t)z * sbias;
  const int m0 = blockIdx.y * 128, n0 = blockIdx.x * 128;
  __shared__ alignas(16) bf16 As[128 * 32];
  __shared__ alignas(16) bf16 Bs[128 * 32];
  const int tid = threadIdx.x, lane = tid & 63, w = tid >> 6;
  const int wm = (w & 1) * 64, wn = (w >> 1) * 64;
  f32x4 acc[4][4] = {};

  // staging: chunk c=(j*4+w)*64+lane; row=c>>2; lds gets global chunk
  // q = qpos ^ ((row>>1)&3)  (XOR swizzle -> frag reads are 2-way = free)
  int c0 = w * 64 + lane, c1 = (4 + w) * 64 + lane;
  int ra0 = c0 >> 2, qa0 = (c0 & 3) ^ ((ra0 >> 1) & 3);
  int ra1 = c1 >> 2, qa1 = (c1 & 3) ^ ((ra1 >> 1) & 3);
  const bf16* gA0 = A + (int64_t)(m0 + ra0) * lda + qa0 * 8;
  const bf16* gA1 = A + (int64_t)(m0 + ra1) * lda + qa1 * 8;
  const bf16* gB0 = Bm + (int64_t)(n0 + ra0) * ldb + qa0 * 8;
  const bf16* gB1 = Bm + (int64_t)(n0 + ra1) * ldb + qa1 * 8;
  bf16* lA0 = As + w * 512;        // wave-uniform LDS bases
  bf16* lA1 = As + (4 + w) * 512;
  bf16* lB0 = Bs + w * 512;
  bf16* lB1 = Bs + (4 + w) * 512;

  const int rl = lane & 15, qq = lane >> 4;
  for (int k0 = 0; k0 < K; k0 += 32) {
    __syncthreads();
    gload16(gA0 + k0, lA0);
    gload16(gA1 + k0, lA1);
    gload16(gB0 + k0, lB0);
    gload16(gB1 + k0, lB1);
    __syncthreads();  // drains vmcnt then barrier
    bf16x8 af[4], bv[4];
#pragma unroll
    for (int i = 0; i < 4; i++) {
      int r = wm + i * 16 + rl;
      af[i] = *(const bf16x8*)(As + r * 32 + (qq ^ ((r >> 1) & 3)) * 8);
    }
#pragma unroll
    for (int j = 0; j < 4; j++) {
      int r = wn + j * 16 + rl;
      bv[j] = *(const bf16x8*)(Bs + r * 32 + (qq ^ ((r >> 1) & 3)) * 8);
    }
#pragma unroll
    for (int i = 0; i < 4; i++)
#pragma unroll
      for (int j = 0; j < 4; j++)
        acc[i][j] = __builtin_amdgcn_mfma_f32_16x16x32_bf16(af[i], bv[j],
                                                            acc[i][j], 0, 0, 0);
  }
#pragma unroll
  for (int j = 0; j < 4; j++) {
    int gn = n0 + wn + j * 16 + rl;
    float bb = bias ? bias[gn] : 0.0f;
#pragma unroll
    for (int i = 0; i < 4; i++) {
      int gm0 = m0 + wm + i * 16 + qq * 4;
#pragma unroll
      for (int r = 0; r < 4; r++)
        C[(int64_t)(gm0 + r) * ldc + gn] = (bf16)(acc[i][j][r] + bb);
    }
  }
}

// -------------------- small GEMM (M=64): C = A @ B^T -----------------------
// 64 rows x 64-col tiles, templated BK, batched (z) + split-K (blockIdx.y).
// EPI: 0=none, 1=relu, 2=sigmoid(val)*aux  (gated memory).
template <int BK, int EPI, typename OutT>
__global__ __launch_bounds__(256) void gemm_bt_small(
    const bf16* __restrict__ A, int lda, int64_t sA,
    const bf16* __restrict__ Bm, int ldb, int64_t sB,
    OutT* __restrict__ C, int ldc, int64_t sC, int64_t sCk,
    const float* __restrict__ bias, float scale,
    const bf16* __restrict__ aux, int ldaux, int klen) {
  const int z = blockIdx.z, kblk = blockIdx.y;
  A += (int64_t)z * sA + (int64_t)kblk * klen;
  Bm += (int64_t)z * sB + (int64_t)kblk * klen;
  C += (int64_t)z * sC + (int64_t)kblk * sCk;
  const int n0 = blockIdx.x * 64;
  constexpr int CPR = BK / 8;   // 16B chunks per row
  constexpr int J = BK / 32;    // staging issues per matrix per thread
  __shared__ alignas(16) bf16 As[64 * BK];
  __shared__ alignas(16) bf16 Bs[64 * BK];
  const int tid = threadIdx.x, lane = tid & 63, w = tid >> 6;
  const int rl = lane & 15, qq = lane >> 4;
  f32x4 acc[4] = {};

  const bf16 *gA[J], *gB[J];
  bf16 *lA[J], *lB[J];
#pragma unroll
  for (int j = 0; j < J; j++) {
    int c = (j * 4 + w) * 64 + lane;
    int r = c / CPR, qp = c % CPR;
    int q = qp ^ (r & 7);
    gA[j] = A + (int64_t)r * lda + q * 8;
    gB[j] = Bm + (int64_t)(n0 + r) * ldb + q * 8;
    lA[j] = As + (j * 4 + w) * 512;
    lB[j] = Bs + (j * 4 + w) * 512;
  }
  for (int k0 = 0; k0 < klen; k0 += BK) {
    __syncthreads();
#pragma unroll
    for (int j = 0; j < J; j++) {
      gload16(gA[j] + k0, lA[j]);
      gload16(gB[j] + k0, lB[j]);
    }
    __syncthreads();
#pragma unroll
    for (int kk = 0; kk < BK / 32; kk++) {
      int ar = w * 16 + rl;
      int q = kk * 4 + qq;
      bf16x8 af = *(const bf16x8*)(As + ar * BK + (q ^ (ar & 7)) * 8);
#pragma unroll
      for (int j = 0; j < 4; j++) {
        int br = j * 16 + rl;
        bf16x8 bv = *(const bf16x8*)(Bs + br * BK + (q ^ (br & 7)) * 8);
        acc[j] = __builtin_amdgcn_mfma_f32_16x16x32_bf16(af, bv, acc[j], 0, 0, 0);
      }
    }
  }
#pragma unroll
  for (int j = 0; j < 4; j++) {
    int gn = n0 + j * 16 + rl;
    float bb = bias ? bias[gn] : 0.0f;
#pragma unroll
    for (int r = 0; r < 4; r++) {
      int gm = w * 16 + qq * 4 + r;
      float val = (acc[j][r] + bb) * scale;
      if constexpr (EPI == 1) val = fmaxf(val, 0.0f);
      if constexpr (EPI == 2) {
        float g = 1.0f / (1.0f + __expf(-val));
        val = g * (float)aux[(int64_t)gm * ldaux + gn];
      }
      C[(int64_t)gm * ldc + gn] = (OutT)val;
    }
  }
}

// ------------------------------- softmax -----------------------------------
// one block per (h,b) row of 8192 fp32 scores; row held in registers.
__global__ __launch_bounds__(256) void softmax_kernel(
    const float* __restrict__ scores, bf16* __restrict__ attn) {
  int row = blockIdx.x;
  const float4* s = (const float4*)(scores + (int64_t)row * M_);
  bf16* a = attn + (int64_t)row * M_;
  int t = threadIdx.x;
  float4 v[8];
  float mx = -3.4e38f;
#pragma unroll
  for (int j = 0; j < 8; j++) {
    v[j] = s[j * 256 + t];
    mx = fmaxf(mx, fmaxf(fmaxf(v[j].x, v[j].y), fmaxf(v[j].z, v[j].w)));
  }
#pragma unroll
  for (int m = 32; m; m >>= 1) mx = fmaxf(mx, __shfl_xor(mx, m, 64));
  __shared__ float red[4];
  if ((t & 63) == 0) red[t >> 6] = mx;
  __syncthreads();
  mx = fmaxf(fmaxf(red[0], red[1]), fmaxf(red[2], red[3]));
  float sum = 0.f;
#pragma unroll
  for (int j = 0; j < 8; j++) {
    v[j].x = __expf(v[j].x - mx); v[j].y = __expf(v[j].y - mx);
    v[j].z = __expf(v[j].z - mx); v[j].w = __expf(v[j].w - mx);
    sum += v[j].x + v[j].y + v[j].z + v[j].w;
  }
#pragma unroll
  for (int m = 32; m; m >>= 1) sum += __shfl_xor(sum, m, 64);
  __syncthreads();
  if ((t & 63) == 0) red[t >> 6] = sum;
  __syncthreads();
  sum = red[0] + red[1] + red[2] + red[3];
  float rinv = 1.0f / sum;
#pragma unroll
  for (int j = 0; j < 8; j++) {
    bf16x4 o = { (bf16)(v[j].x * rinv), (bf16)(v[j].y * rinv),
                 (bf16)(v[j].z * rinv), (bf16)(v[j].w * rinv) };
    *(bf16x4*)(a + (int64_t)(j * 256 + t) * 4) = o;
  }
}

// sum split-K ctx partials: part[h][ks][b][d] -> ctx[b][h*64+d]
__global__ __launch_bounds__(256) void ctx_reduce(const float* __restrict__ part,
                                                  bf16* __restrict__ ctx) {
  int t = blockIdx.x * 256 + threadIdx.x;
  int h = t >> 12, b = (t >> 6) & 63, d = t & 63;
  float s = 0.f;
#pragma unroll
  for (int ks = 0; ks < 8; ks++)
    s += part[((int64_t)(h * 8 + ks) * 64 + b) * 64 + d];
  ctx[(int64_t)b * D_ + h * 64 + d] = (bf16)s;
}

// ------------------------------- launch ------------------------------------
extern "C" void kernel_launch(void* const* d_in, const int* in_sizes, int n_in,
                              void* d_out, int out_size, void* d_ws,
                              size_t ws_size, hipStream_t stream) {
  (void)in_sizes; (void)n_in; (void)out_size;
  const float* x    = (const float*)d_in[0];
  const float* mk   = (const float*)d_in[1];
  const float* mv   = (const float*)d_in[2];
  const float* Wq   = (const float*)d_in[3];
  const float* bq   = (const float*)d_in[4];
  const float* Wk   = (const float*)d_in[5];
  const float* bk   = (const float*)d_in[6];
  const float* Wv   = (const float*)d_in[7];
  const float* bv   = (const float*)d_in[8];
  const float* inw  = (const float*)d_in[9];
  const float* inb  = (const float*)d_in[10];
  const float* outw = (const float*)d_in[11];
  const float* outb = (const float*)d_in[12];
  const float* gW1  = (const float*)d_in[13];
  const float* gb1  = (const float*)d_in[14];
  const float* gW2  = (const float*)d_in[15];
  const float* gb2  = (const float*)d_in[16];
  const float* iW1  = (const float*)d_in[17];
  const float* ib1  = (const float*)d_in[18];
  const float* iW2  = (const float*)d_in[19];
  const float* ib2  = (const float*)d_in[20];

  char* ws = (char*)d_ws;
  size_t off = 0;
  auto alloc = [&](size_t bytes) {
    char* p = ws + off;
    off += (bytes + 255) & ~(size_t)255;
    return p;
  };
  bf16* mkmv  = (bf16*)alloc((size_t)2 * M_ * D_ * 2);  // reused as scores later
  bf16* inpj  = (bf16*)alloc((size_t)3 * D_ * D_ * 2);
  bf16* WT    = (bf16*)alloc((size_t)3 * D_ * D_ * 2);
  bf16* Wc    = (bf16*)alloc((size_t)3 * D_ * D_ * 2);
  float* bc   = (float*)alloc(3 * D_ * 4);
  bf16* xms   = (bf16*)alloc((size_t)B_ * 2 * D_ * 2);
  bf16* xgm   = (bf16*)alloc((size_t)B_ * 2 * D_ * 2);
  bf16* qh    = (bf16*)alloc((size_t)B_ * D_ * 2);
  bf16* khvh  = (bf16*)alloc((size_t)2 * M_ * D_ * 2);
  bf16* vhT   = (bf16*)alloc((size_t)M_ * D_ * 2);
  bf16* attn  = (bf16*)alloc((size_t)H_ * B_ * M_ * 2);
  float* part = (float*)alloc((size_t)16 * 8 * 64 * 64 * 4);
  bf16* ctx   = (bf16*)alloc((size_t)B_ * D_ * 2);
  bf16* g1    = (bf16*)alloc((size_t)B_ * D_ * 2);
  bf16* h1    = (bf16*)alloc((size_t)B_ * 2 * D_ * 2);
  bf16* gW1b  = (bf16*)alloc((size_t)D_ * 2 * D_ * 2);
  bf16* gW2b  = (bf16*)alloc((size_t)D_ * D_ * 2);
  bf16* iW1b  = (bf16*)alloc((size_t)2 * D_ * 2 * D_ * 2);
  bf16* iW2b  = (bf16*)alloc((size_t)D_ * 2 * D_ * 2);
  bf16* outwb = (bf16*)alloc((size_t)D_ * D_ * 2);
  float* scores = (float*)mkmv;  // alias: mk/mv bf16 dead after kh/vh GEMM
  if (ws_size < off) return;     // workspace too small (deterministic no-op)

  // 1) convert everything to bf16 (x also lands in concat buffers)
  CvtArgs ca;
  ca.d[0] = { mk,  mkmv,            M_ * D_,     M_ * D_,     M_ * D_ };
  ca.d[1] = { mv,  mkmv + M_ * D_,  M_ * D_,     M_ * D_,     M_ * D_ };
  ca.d[2] = { inw, inpj,            3 * D_ * D_, 3 * D_ * D_, 3 * D_ * D_ };
  ca.d[3] = { gW1, gW1b,            D_ * 2 * D_, D_ * 2 * D_, D_ * 2 * D_ };
  ca.d[4] = { gW2, gW2b,            D_ * D_,     D_ * D_,     D_ * D_ };
  ca.d[5] = { iW1, iW1b,        2 * D_ * 2 * D_, 2 * D_ * 2 * D_, 2 * D_ * 2 * D_ };
  ca.d[6] = { iW2, iW2b,            D_ * 2 * D_, D_ * 2 * D_, D_ * 2 * D_ };
  ca.d[7] = { outw, outwb,          D_ * D_,     D_ * D_,     D_ * D_ };
  ca.d[8] = { x,   xms,             B_ * D_,     D_,          2 * D_ };
  ca.d[9] = { x,   xgm,             B_ * D_,     D_,          2 * D_ };
  cvt_multi<<<dim3(8192, 10), 256, 0, stream>>>(ca);

  // 2) W^T (bf16) for the weight-combine GEMMs
  transpose_cvt3<<<dim3(32, 32, 3), 256, 0, stream>>>(Wq, Wk, Wv, WT);

  // 3) combined biases bc = Wi @ b + bi
  bias_combine<<<dim3(D_, 3), 256, 0, stream>>>(inw, inb, bq, bk, bv, bc);

  // 4) Wc_z = Wi_z @ W_z  (batched 1024^3, C[n,k] = sum_l Wi[n,l] * WT[k,l])
  gemm_bt_big<<<dim3(8, 8, 3), 256, 0, stream>>>(
      inpj, D_, (int64_t)D_ * D_, WT, D_, (int64_t)D_ * D_,
      Wc, D_, (int64_t)D_ * D_, nullptr, 0, D_);

  // 5) kh = mk @ Wck^T + bck ; vh = mv @ Wcv^T + bcv  (batched)
  gemm_bt_big<<<dim3(8, 64, 2), 256, 0, stream>>>(
      mkmv, D_, (int64_t)M_ * D_, Wc + (int64_t)D_ * D_, D_, (int64_t)D_ * D_,
      khvh, D_, (int64_t)M_ * D_, bc + D_, D_, D_);

  // 6) qh = (x @ Wcq^T + bcq) * 1/sqrt(HD)
  gemm_bt_small<128, 0, bf16><<<dim3(16, 1, 1), 256, 0, stream>>>(
      xms, 2 * D_, 0, Wc, D_, 0, qh, D_, 0, 0, bc, 0.125f, nullptr, 0, D_);

  // 7) scores[h,b,m] (fp32, aliases mkmv)
  gemm_bt_small<64, 0, float><<<dim3(128, 1, 16), 256, 0, stream>>>(
      qh, D_, 64, khvh, D_, 64, scores, M_, (int64_t)B_ * M_, 0,
      nullptr, 1.0f, nullptr, 0, 64);

  // 8) softmax rows -> attn (bf16)
  softmax_kernel<<<dim3(H_ * B_), 256, 0, stream>>>(scores, attn);

  // 9) vhT[n][m] for ctx GEMM B-operand
  transpose_vh<<<dim3(16, 128), 256, 0, stream>>>(khvh + (int64_t)M_ * D_, vhT);

  // 10) ctx partials (split-K x8 per head) + reduce
  gemm_bt_small<128, 0, float><<<dim3(1, 8, 16), 256, 0, stream>>>(
      attn, M_, (int64_t)B_ * M_, vhT, M_, (int64_t)64 * M_,
      part, 64, (int64_t)8 * 4096, 4096, nullptr, 1.0f, nullptr, 0, 1024);
  ctx_reduce<<<dim3(256), 256, 0, stream>>>(part, ctx);

  // 11) memory_signal -> xms[:, D:]
  gemm_bt_small<128, 0, bf16><<<dim3(16, 1, 1), 256, 0, stream>>>(
      ctx, D_, 0, outwb, D_, 0, xms + D_, 2 * D_, 0, 0, outb, 1.0f,
      nullptr, 0, D_);

  // 12) g1 = relu([x,ms] @ gW1^T + gb1)
  gemm_bt_small<128, 1, bf16><<<dim3(16, 1, 1), 256, 0, stream>>>(
      xms, 2 * D_, 0, gW1b, 2 * D_, 0, g1, D_, 0, 0, gb1, 1.0f,
      nullptr, 0, 2 * D_);

  // 13) gated_memory = sigmoid(g1 @ gW2^T + gb2) * ms -> xgm[:, D:]
  gemm_bt_small<128, 2, bf16><<<dim3(16, 1, 1), 256, 0, stream>>>(
      g1, D_, 0, gW2b, D_, 0, xgm + D_, 2 * D_, 0, 0, gb2, 1.0f,
      xms + D_, 2 * D_, D_);

  // 14) h1 = relu([x,gated] @ iW1^T + ib1)
  gemm_bt_small<128, 1, bf16><<<dim3(32, 1, 1), 256, 0, stream>>>(
      xgm, 2 * D_, 0, iW1b, 2 * D_, 0, h1, 2 * D_, 0, 0, ib1, 1.0f,
      nullptr, 0, 2 * D_);

  // 15) out = h1 @ iW2^T + ib2 (fp32)
  gemm_bt_small<128, 0, float><<<dim3(16, 1, 1), 256, 0, stream>>>(
      h1, 2 * D_, 0, iW2b, 2 * D_, 0, (float*)d_out, D_, 0, 0, ib2, 1.0f,
      nullptr, 0, 2 * D_);
}